// Round 1
// baseline (1125.393 us; speedup 1.0000x reference)
//
#include <hip/hip_runtime.h>
#include <math.h>

// LADMM unrolled network, MI355X — Woodbury operator form.
// x_new = y @ invM, invM = Cinv - G^T S^-1 G  (C = a*I + g*DtD circulant)
// Cinv applied as EXACT bidirectional exponential IIR (c_d = K*rho^|d|),
// computed with weighted wave scans in registers -> no rs2 LDS buffer.
#define NS 300
#define NM 9
#define NB 131072
#define NL 5
#define GPITCH 320     // G/H LDS row pitch (zero-padded j in [300,320))

// workspace layout (floats)
#define OFF_C 0        // [NL][NS]     circulant kernel of C^-1 (setup only)
#define OFF_G 1536     // [NL][NM][NS] G = A C^-1
#define OFF_H 15360    // [NL][NM][NS] H = S^-1 G

// ---------------- setup 1: first column of C^-1 per layer (DFT) ----------
__global__ void k_cinv(const float* __restrict__ alpha,
                       const float* __restrict__ gamma,
                       float* __restrict__ cbuf) {
  __shared__ double costab[NS];
  __shared__ double invlam[NS];
  const int l = blockIdx.x;
  const int j = threadIdx.x;
  const double al = (double)alpha[l], g = (double)gamma[l];
  const double tpn = 6.283185307179586476925286766559 / (double)NS;
  if (j < NS) {
    double cj = cos(tpn * (double)j);
    costab[j] = cj;
    invlam[j] = 1.0 / (al + 2.0 * g * (1.0 - cj));
  }
  __syncthreads();
  if (j < NS) {
    double s = 0.0;
    for (int m = 0; m < NS; ++m) s += costab[(j * m) % NS] * invlam[m];
    cbuf[l * NS + j] = (float)(s / (double)NS);
  }
}

// ---------------- setup 2: G[l][k][j] = sum_i A[k][i] * c[(i-j) mod NS] ---
__global__ void k_G(const float* __restrict__ A, const float* __restrict__ cbuf,
                    float* __restrict__ Gbuf) {
  const int l = blockIdx.x / NM, kk = blockIdx.x % NM;
  const int j = threadIdx.x;
  if (j >= NS) return;
  const float* c = cbuf + l * NS;
  const float* Ak = A + kk * NS;
  float s = 0.f;
  for (int i = 0; i < NS; ++i) {
    int d = i - j; if (d < 0) d += NS;
    s = fmaf(Ak[i], c[d], s);
  }
  Gbuf[(l * NM + kk) * NS + j] = s;
}

// ---------------- setup 3: S = I + G A^T ; invert 9x9 ; H = S^-1 G -------
__global__ void k_SH(const float* __restrict__ A, const float* __restrict__ Gbuf,
                     float* __restrict__ Hbuf) {
  __shared__ float Si[9][18];
  const int l = blockIdx.x, t = threadIdx.x;
  const float* G = Gbuf + l * NM * NS;
  if (t < 81) {
    int p = t / 9, q = t % 9;
    float s = (p == q) ? 1.f : 0.f;
    const float* Gp = G + p * NS;
    const float* Aq = A + q * NS;
    for (int j = 0; j < NS; ++j) s = fmaf(Gp[j], Aq[j], s);
    Si[p][q] = s;
    Si[p][q + 9] = (p == q) ? 1.f : 0.f;
  }
  __syncthreads();
  if (t == 0) {
    for (int p = 0; p < 9; ++p) {
      float piv = 1.f / Si[p][p];
      for (int q = 0; q < 18; ++q) Si[p][q] *= piv;
      for (int r = 0; r < 9; ++r) if (r != p) {
        float f = Si[r][p];
        for (int q = 0; q < 18; ++q) Si[r][q] -= f * Si[p][q];
      }
    }
  }
  __syncthreads();
  for (int idx = t; idx < NM * NS; idx += blockDim.x) {
    int p = idx / NS, j = idx % NS;
    float s = 0.f;
    #pragma unroll
    for (int q = 0; q < 9; ++q) s = fmaf(Si[p][q + 9], G[q * NS + j], s);
    Hbuf[l * NM * NS + idx] = s;
  }
}

// ---------------- main fused kernel: 8 rows/block, scan-based Cinv --------
__global__ __launch_bounds__(256, 5)
void k_main(const float* __restrict__ b, const float* __restrict__ A,
            const float* __restrict__ gam, const float* __restrict__ lamv,
            const float* __restrict__ alp,
            const float* __restrict__ Gbuf, const float* __restrict__ Hbuf,
            float* __restrict__ out) {
  __shared__ float Gl[NM * GPITCH];     // per-layer G (zero-padded cols)
  __shared__ float Hl[NM * GPITCH];     // per-layer H

  const int tid = threadIdx.x;
  const int tx = tid & 63;
  const int wv = tid >> 6;              // wave 0..3, owns rows 2*wv..2*wv+1
  const int col = tx * 5;
  const bool live = (tx < 60);
  const int prevlane = (tx == 0) ? 59 : (tx - 1);
  const int row0 = blockIdx.x * 8 + wv * 2;

  // one-time zero pads (never overwritten later)
  if (tid < 180) {
    int q = tid / 20, j2 = 300 + (tid % 20);
    Gl[q * GPITCH + j2] = 0.f;
    Hl[q * GPITCH + j2] = 0.f;
  }

  // per-row state: x, eta, tau, z (= eta - g*u), y, bA
  float x[2][5], eta[2][5], tau[2][5], z[2][5], y[2][5], bA[2][5];
  #pragma unroll
  for (int r = 0; r < 2; ++r)
    #pragma unroll
    for (int c = 0; c < 5; ++c) { x[r][c] = 1.f; eta[r][c] = 0.f; tau[r][c] = 0.f; bA[r][c] = 0.f; }

  // bA = b @ A (constant across layers)
  #pragma unroll
  for (int r = 0; r < 2; ++r) {
    float bb0[NM];
    #pragma unroll
    for (int k = 0; k < NM; ++k) bb0[k] = b[(size_t)(row0 + r) * NM + k];
    if (live) {
      #pragma unroll
      for (int c = 0; c < 5; ++c) {
        float s = 0.f;
        #pragma unroll
        for (int k = 0; k < NM; ++k) s = fmaf(bb0[k], A[k * NS + col + c], s);
        bA[r][c] = s;
      }
    }
  }

  for (int l = 0; l < NL; ++l) {
    const float g = gam[l], lm = lamv[l], al = alp[l];
    const float ig = 1.f / g, ia = 1.f / al, thr = lm * ig;
    // analytic Cinv kernel: c_d = Kc * rho^|d|
    const float m2 = al + 2.f * g;
    const float disc = sqrtf(fmaxf(fmaf(m2, m2, -4.f * g * g), 0.f));
    float rho = (m2 - disc) / (2.f * g);
    rho = fmaxf(rho, 1e-30f);                 // guard log2f(0)
    const float Kc = 1.f / disc;
    const float rp2 = rho * rho, rp3 = rp2 * rho, rp4 = rp2 * rp2, rp5 = rp4 * rho;
    const float l2r = log2f(rho);
    const float rcf = exp2f((float)col * l2r);          // rho^col
    const float rcb = exp2f((float)(295 - col) * l2r);  // rho^(295-col)

    __syncthreads();   // prior layer's LDS reads complete before overwrite

    // stage G, H for this layer (coalesced float4)
    {
      const float* Gg = Gbuf + l * NM * NS;
      const float* Hg = Hbuf + l * NM * NS;
      for (int i = tid; i < (NM * NS) / 4; i += 256) {
        int q = i / 75, jj = (i % 75) * 4;
        *(float4*)&Gl[q * GPITCH + jj] = *(const float4*)&Gg[q * NS + jj];
        *(float4*)&Hl[q * GPITCH + jj] = *(const float4*)&Hg[q * NS + jj];
      }
    }

    // Phase A: u, w, residual y (registers only; no LDS)
    #pragma unroll
    for (int r = 0; r < 2; ++r) {
      float xp = __shfl(x[r][4], prevlane, 64);
      #pragma unroll
      for (int c = 0; c < 5; ++c) {
        float xl = (c == 0) ? xp : x[r][c - 1];
        float v = (xl - x[r][c]) + eta[r][c] * ig;
        float av = fabsf(v) - thr;
        float uu = (av > 0.f) ? copysignf(av, v) : 0.f;
        float ww = fmaf(tau[r][c], ia, x[r][c]);
        ww = (ww > 0.f) ? ww : 0.f;
        float awv = al * ww;
        float yv = bA[r][c] + awv - tau[r][c] + g * uu - eta[r][c];
        y[r][c] = live ? yv : 0.f;           // dead lanes MUST be 0 for scans
        z[r][c] = fmaf(-g, uu, eta[r][c]);   // z = eta - g*u
      }
    }

    // x_conv = Kc * (f + b - y): bidirectional exponential IIR via wave scans
    float acc[2][5];
    #pragma unroll
    for (int r = 0; r < 2; ++r) {
      // forward f[j] = y[j] + rho*f[j-1]
      float f0 = y[r][0];
      float f1 = fmaf(rho, f0, y[r][1]);
      float f2 = fmaf(rho, f1, y[r][2]);
      float f3 = fmaf(rho, f2, y[r][3]);
      float f4 = fmaf(rho, f3, y[r][4]);
      float cf = f4;                     // per-lane carry (zero-in local last)
      float rw = rp5;                    // rho^(5*d) weights
      #pragma unroll
      for (int d = 1; d <= 32; d <<= 1) {
        float t = __shfl_up(cf, d, 64);
        cf = fmaf((tx >= d) ? rw : 0.f, t, cf);
        rw *= rw;
      }
      float Ef = __shfl_up(cf, 1, 64);   // exclusive carry = f_lin[col-1]
      Ef = (tx >= 1) ? Ef : 0.f;
      float Fe = __shfl(cf, 59, 64);     // f_lin[299] for circular wrap
      Ef = fmaf(rcf, Fe, Ef);

      // backward b[j] = y[j] + rho*b[j+1]
      float g4 = y[r][4];
      float g3 = fmaf(rho, g4, y[r][3]);
      float g2 = fmaf(rho, g3, y[r][2]);
      float g1 = fmaf(rho, g2, y[r][1]);
      float g0 = fmaf(rho, g1, y[r][0]);
      float cb = g0;
      rw = rp5;
      #pragma unroll
      for (int d = 1; d <= 32; d <<= 1) {
        float t = __shfl_down(cb, d, 64);
        cb = fmaf((tx <= 63 - d) ? rw : 0.f, t, cb);
        rw *= rw;
      }
      float Eb = __shfl_down(cb, 1, 64); // exclusive carry = b_lin[col+5]
      Eb = (tx <= 62) ? Eb : 0.f;
      float Be = __shfl(cb, 0, 64);      // b_lin[0] for circular wrap
      Eb = fmaf(rcb, Be, Eb);

      // fixups: f[c] += rho^(c+1)*Ef ; b[c] += rho^(5-c)*Eb
      f0 = fmaf(rho, Ef, f0);  g0 = fmaf(rp5, Eb, g0);
      f1 = fmaf(rp2, Ef, f1);  g1 = fmaf(rp4, Eb, g1);
      f2 = fmaf(rp3, Ef, f2);  g2 = fmaf(rp3, Eb, g2);
      f3 = fmaf(rp4, Ef, f3);  g3 = fmaf(rp2, Eb, g3);
      f4 = fmaf(rp5, Ef, f4);  g4 = fmaf(rho, Eb, g4);

      acc[r][0] = Kc * ((f0 + g0) - y[r][0]);
      acc[r][1] = Kc * ((f1 + g1) - y[r][1]);
      acc[r][2] = Kc * ((f2 + g2) - y[r][2]);
      acc[r][3] = Kc * ((f3 + g3) - y[r][3]);
      acc[r][4] = Kc * ((f4 + g4) - y[r][4]);
    }

    __syncthreads();   // Gl/Hl staged

    // Woodbury correction: acc -= (y.G[q]) * H[q], q in groups of 3
    #pragma unroll
    for (int qg = 0; qg < NM; qg += 3) {
      float p00 = 0.f, p01 = 0.f, p02 = 0.f, p10 = 0.f, p11 = 0.f, p12 = 0.f;
      #pragma unroll
      for (int c = 0; c < 5; ++c) {
        float gv0 = Gl[(qg + 0) * GPITCH + col + c];
        float gv1 = Gl[(qg + 1) * GPITCH + col + c];
        float gv2 = Gl[(qg + 2) * GPITCH + col + c];
        p00 = fmaf(y[0][c], gv0, p00); p10 = fmaf(y[1][c], gv0, p10);
        p01 = fmaf(y[0][c], gv1, p01); p11 = fmaf(y[1][c], gv1, p11);
        p02 = fmaf(y[0][c], gv2, p02); p12 = fmaf(y[1][c], gv2, p12);
      }
      #pragma unroll
      for (int m = 32; m >= 1; m >>= 1) {
        p00 += __shfl_xor(p00, m, 64);
        p01 += __shfl_xor(p01, m, 64);
        p02 += __shfl_xor(p02, m, 64);
        p10 += __shfl_xor(p10, m, 64);
        p11 += __shfl_xor(p11, m, 64);
        p12 += __shfl_xor(p12, m, 64);
      }
      #pragma unroll
      for (int c = 0; c < 5; ++c) {
        float h0 = Hl[(qg + 0) * GPITCH + col + c];
        float h1 = Hl[(qg + 1) * GPITCH + col + c];
        float h2 = Hl[(qg + 2) * GPITCH + col + c];
        acc[0][c] = fmaf(-p00, h0, acc[0][c]);
        acc[1][c] = fmaf(-p10, h0, acc[1][c]);
        acc[0][c] = fmaf(-p01, h1, acc[0][c]);
        acc[1][c] = fmaf(-p11, h1, acc[1][c]);
        acc[0][c] = fmaf(-p02, h2, acc[0][c]);
        acc[1][c] = fmaf(-p12, h2, acc[1][c]);
      }
    }

    // x = acc; dual updates via z:
    //   eta' = g*(xl'-x') + z ; tau' = al*x' + bA - y - z
    #pragma unroll
    for (int r = 0; r < 2; ++r) {
      #pragma unroll
      for (int c = 0; c < 5; ++c) x[r][c] = acc[r][c];
      float xp = __shfl(x[r][4], prevlane, 64);
      #pragma unroll
      for (int c = 0; c < 5; ++c) {
        float xl = (c == 0) ? xp : x[r][c - 1];
        eta[r][c] = fmaf(g, xl - x[r][c], z[r][c]);
        tau[r][c] = fmaf(al, x[r][c], (bA[r][c] - y[r][c]) - z[r][c]);
      }
    }
  }

  if (live) {
    #pragma unroll
    for (int r = 0; r < 2; ++r) {
      size_t o = (size_t)(row0 + r) * NS + col;
      #pragma unroll
      for (int c = 0; c < 5; ++c) out[o + c] = x[r][c];
    }
  }
}

extern "C" void kernel_launch(void* const* d_in, const int* in_sizes, int n_in,
                              void* d_out, int out_size, void* d_ws, size_t ws_size,
                              hipStream_t stream) {
  const float* b   = (const float*)d_in[0];
  const float* A   = (const float*)d_in[2];
  const float* gam = (const float*)d_in[3];
  const float* lm  = (const float*)d_in[4];
  const float* al  = (const float*)d_in[5];
  float* out = (float*)d_out;
  float* ws  = (float*)d_ws;

  float* cbuf = ws + OFF_C;
  float* Gbuf = ws + OFF_G;
  float* Hbuf = ws + OFF_H;

  k_cinv<<<dim3(NL), dim3(320), 0, stream>>>(al, gam, cbuf);
  k_G   <<<dim3(NL * NM), dim3(320), 0, stream>>>(A, cbuf, Gbuf);
  k_SH  <<<dim3(NL), dim3(128), 0, stream>>>(A, Gbuf, Hbuf);
  k_main<<<dim3(NB / 8), dim3(256), 0, stream>>>(b, A, gam, lm, al,
                                                 Gbuf, Hbuf, out);
}

// Round 2
// 912.794 us; speedup vs baseline: 1.2329x; 1.2329x over previous
//
#include <hip/hip_runtime.h>
#include <math.h>

// LADMM unrolled network, MI355X — Woodbury operator form.
// x_new = y @ invM, invM = Cinv - G^T S^-1 G  (C = a*I + g*DtD circulant)
// Cinv applied as EXACT bidirectional exponential IIR (c_d = K*rho^|d|),
// computed with weighted wave scans in registers -> no rs2 LDS buffer.
#define NS 300
#define NM 9
#define NB 131072
#define NL 5
#define GPITCH 320     // G/H LDS row pitch (zero-padded j in [300,320))

// workspace layout (floats)
#define OFF_C 0        // [NL][NS]     circulant kernel of C^-1 (setup only)
#define OFF_G 1536     // [NL][NM][NS] G = A C^-1
#define OFF_H 15360    // [NL][NM][NS] H = S^-1 G

// ---------------- setup 1: first column of C^-1 per layer (DFT) ----------
__global__ void k_cinv(const float* __restrict__ alpha,
                       const float* __restrict__ gamma,
                       float* __restrict__ cbuf) {
  __shared__ double costab[NS];
  __shared__ double invlam[NS];
  const int l = blockIdx.x;
  const int j = threadIdx.x;
  const double al = (double)alpha[l], g = (double)gamma[l];
  const double tpn = 6.283185307179586476925286766559 / (double)NS;
  if (j < NS) {
    double cj = cos(tpn * (double)j);
    costab[j] = cj;
    invlam[j] = 1.0 / (al + 2.0 * g * (1.0 - cj));
  }
  __syncthreads();
  if (j < NS) {
    double s = 0.0;
    for (int m = 0; m < NS; ++m) s += costab[(j * m) % NS] * invlam[m];
    cbuf[l * NS + j] = (float)(s / (double)NS);
  }
}

// ---------------- setup 2: G[l][k][j] = sum_i A[k][i] * c[(i-j) mod NS] ---
__global__ void k_G(const float* __restrict__ A, const float* __restrict__ cbuf,
                    float* __restrict__ Gbuf) {
  const int l = blockIdx.x / NM, kk = blockIdx.x % NM;
  const int j = threadIdx.x;
  if (j >= NS) return;
  const float* c = cbuf + l * NS;
  const float* Ak = A + kk * NS;
  float s = 0.f;
  for (int i = 0; i < NS; ++i) {
    int d = i - j; if (d < 0) d += NS;
    s = fmaf(Ak[i], c[d], s);
  }
  Gbuf[(l * NM + kk) * NS + j] = s;
}

// ---------------- setup 3: S = I + G A^T ; invert 9x9 ; H = S^-1 G -------
__global__ void k_SH(const float* __restrict__ A, const float* __restrict__ Gbuf,
                     float* __restrict__ Hbuf) {
  __shared__ float Si[9][18];
  const int l = blockIdx.x, t = threadIdx.x;
  const float* G = Gbuf + l * NM * NS;
  if (t < 81) {
    int p = t / 9, q = t % 9;
    float s = (p == q) ? 1.f : 0.f;
    const float* Gp = G + p * NS;
    const float* Aq = A + q * NS;
    for (int j = 0; j < NS; ++j) s = fmaf(Gp[j], Aq[j], s);
    Si[p][q] = s;
    Si[p][q + 9] = (p == q) ? 1.f : 0.f;
  }
  __syncthreads();
  if (t == 0) {
    for (int p = 0; p < 9; ++p) {
      float piv = 1.f / Si[p][p];
      for (int q = 0; q < 18; ++q) Si[p][q] *= piv;
      for (int r = 0; r < 9; ++r) if (r != p) {
        float f = Si[r][p];
        for (int q = 0; q < 18; ++q) Si[r][q] -= f * Si[p][q];
      }
    }
  }
  __syncthreads();
  for (int idx = t; idx < NM * NS; idx += blockDim.x) {
    int p = idx / NS, j = idx % NS;
    float s = 0.f;
    #pragma unroll
    for (int q = 0; q < 9; ++q) s = fmaf(Si[p][q + 9], G[q * NS + j], s);
    Hbuf[l * NM * NS + idx] = s;
  }
}

// ---------------- main fused kernel: 8 rows/block, scan-based Cinv --------
// launch_bounds(256,4): 256-thread block = 4 whole waves; (256,5) rounds to
// 8 waves/EU -> 64-VGPR cap -> catastrophic scratch spill (measured r1:
// 1.09 GB spill traffic). (256,4) caps at 128 VGPR, state (~100) fits.
__global__ __launch_bounds__(256, 4)
void k_main(const float* __restrict__ b, const float* __restrict__ A,
            const float* __restrict__ gam, const float* __restrict__ lamv,
            const float* __restrict__ alp,
            const float* __restrict__ Gbuf, const float* __restrict__ Hbuf,
            float* __restrict__ out) {
  __shared__ float Gl[NM * GPITCH];     // per-layer G (zero-padded cols)
  __shared__ float Hl[NM * GPITCH];     // per-layer H

  const int tid = threadIdx.x;
  const int tx = tid & 63;
  const int wv = tid >> 6;              // wave 0..3, owns rows 2*wv..2*wv+1
  const int col = tx * 5;
  const bool live = (tx < 60);
  const int prevlane = (tx == 0) ? 59 : (tx - 1);
  const int row0 = blockIdx.x * 8 + wv * 2;

  // one-time zero pads (never overwritten later)
  if (tid < 180) {
    int q = tid / 20, j2 = 300 + (tid % 20);
    Gl[q * GPITCH + j2] = 0.f;
    Hl[q * GPITCH + j2] = 0.f;
  }

  // per-row state: x, eta, tau, z (= eta - g*u), y, bA
  float x[2][5], eta[2][5], tau[2][5], z[2][5], y[2][5], bA[2][5];
  #pragma unroll
  for (int r = 0; r < 2; ++r)
    #pragma unroll
    for (int c = 0; c < 5; ++c) { x[r][c] = 1.f; eta[r][c] = 0.f; tau[r][c] = 0.f; bA[r][c] = 0.f; }

  // bA = b @ A (constant across layers)
  #pragma unroll
  for (int r = 0; r < 2; ++r) {
    float bb0[NM];
    #pragma unroll
    for (int k = 0; k < NM; ++k) bb0[k] = b[(size_t)(row0 + r) * NM + k];
    if (live) {
      #pragma unroll
      for (int c = 0; c < 5; ++c) {
        float s = 0.f;
        #pragma unroll
        for (int k = 0; k < NM; ++k) s = fmaf(bb0[k], A[k * NS + col + c], s);
        bA[r][c] = s;
      }
    }
  }

  for (int l = 0; l < NL; ++l) {
    const float g = gam[l], lm = lamv[l], al = alp[l];
    const float ig = 1.f / g, ia = 1.f / al, thr = lm * ig;
    // analytic Cinv kernel: c_d = Kc * rho^|d|
    const float m2 = al + 2.f * g;
    const float disc = sqrtf(fmaxf(fmaf(m2, m2, -4.f * g * g), 0.f));
    float rho = (m2 - disc) / (2.f * g);
    rho = fmaxf(rho, 1e-30f);                 // guard log2f(0)
    const float Kc = 1.f / disc;
    const float rp2 = rho * rho, rp3 = rp2 * rho, rp4 = rp2 * rp2, rp5 = rp4 * rho;
    const float l2r = log2f(rho);
    const float rcf = exp2f((float)col * l2r);          // rho^col
    const float rcb = exp2f((float)(295 - col) * l2r);  // rho^(295-col)

    __syncthreads();   // prior layer's LDS reads complete before overwrite

    // stage G, H for this layer (coalesced float4)
    {
      const float* Gg = Gbuf + l * NM * NS;
      const float* Hg = Hbuf + l * NM * NS;
      for (int i = tid; i < (NM * NS) / 4; i += 256) {
        int q = i / 75, jj = (i % 75) * 4;
        *(float4*)&Gl[q * GPITCH + jj] = *(const float4*)&Gg[q * NS + jj];
        *(float4*)&Hl[q * GPITCH + jj] = *(const float4*)&Hg[q * NS + jj];
      }
    }

    // Phase A: u, w, residual y (registers only; no LDS)
    #pragma unroll
    for (int r = 0; r < 2; ++r) {
      float xp = __shfl(x[r][4], prevlane, 64);
      #pragma unroll
      for (int c = 0; c < 5; ++c) {
        float xl = (c == 0) ? xp : x[r][c - 1];
        float v = (xl - x[r][c]) + eta[r][c] * ig;
        float av = fabsf(v) - thr;
        float uu = (av > 0.f) ? copysignf(av, v) : 0.f;
        float ww = fmaf(tau[r][c], ia, x[r][c]);
        ww = (ww > 0.f) ? ww : 0.f;
        float awv = al * ww;
        float yv = bA[r][c] + awv - tau[r][c] + g * uu - eta[r][c];
        y[r][c] = live ? yv : 0.f;           // dead lanes MUST be 0 for scans
        z[r][c] = fmaf(-g, uu, eta[r][c]);   // z = eta - g*u
      }
    }

    // x_conv = Kc * (f + b - y): bidirectional exponential IIR via wave scans
    float acc[2][5];
    #pragma unroll
    for (int r = 0; r < 2; ++r) {
      // forward f[j] = y[j] + rho*f[j-1]
      float f0 = y[r][0];
      float f1 = fmaf(rho, f0, y[r][1]);
      float f2 = fmaf(rho, f1, y[r][2]);
      float f3 = fmaf(rho, f2, y[r][3]);
      float f4 = fmaf(rho, f3, y[r][4]);
      float cf = f4;                     // per-lane carry (zero-in local last)
      float rw = rp5;                    // rho^(5*d) weights
      #pragma unroll
      for (int d = 1; d <= 32; d <<= 1) {
        float t = __shfl_up(cf, d, 64);
        cf = fmaf((tx >= d) ? rw : 0.f, t, cf);
        rw *= rw;
      }
      float Ef = __shfl_up(cf, 1, 64);   // exclusive carry = f_lin[col-1]
      Ef = (tx >= 1) ? Ef : 0.f;
      float Fe = __shfl(cf, 59, 64);     // f_lin[299] for circular wrap
      Ef = fmaf(rcf, Fe, Ef);

      // backward b[j] = y[j] + rho*b[j+1]
      float g4 = y[r][4];
      float g3 = fmaf(rho, g4, y[r][3]);
      float g2 = fmaf(rho, g3, y[r][2]);
      float g1 = fmaf(rho, g2, y[r][1]);
      float g0 = fmaf(rho, g1, y[r][0]);
      float cb = g0;
      rw = rp5;
      #pragma unroll
      for (int d = 1; d <= 32; d <<= 1) {
        float t = __shfl_down(cb, d, 64);
        cb = fmaf((tx <= 63 - d) ? rw : 0.f, t, cb);
        rw *= rw;
      }
      float Eb = __shfl_down(cb, 1, 64); // exclusive carry = b_lin[col+5]
      Eb = (tx <= 62) ? Eb : 0.f;
      float Be = __shfl(cb, 0, 64);      // b_lin[0] for circular wrap
      Eb = fmaf(rcb, Be, Eb);

      // fixups: f[c] += rho^(c+1)*Ef ; b[c] += rho^(5-c)*Eb
      f0 = fmaf(rho, Ef, f0);  g0 = fmaf(rp5, Eb, g0);
      f1 = fmaf(rp2, Ef, f1);  g1 = fmaf(rp4, Eb, g1);
      f2 = fmaf(rp3, Ef, f2);  g2 = fmaf(rp3, Eb, g2);
      f3 = fmaf(rp4, Ef, f3);  g3 = fmaf(rp2, Eb, g3);
      f4 = fmaf(rp5, Ef, f4);  g4 = fmaf(rho, Eb, g4);

      acc[r][0] = Kc * ((f0 + g0) - y[r][0]);
      acc[r][1] = Kc * ((f1 + g1) - y[r][1]);
      acc[r][2] = Kc * ((f2 + g2) - y[r][2]);
      acc[r][3] = Kc * ((f3 + g3) - y[r][3]);
      acc[r][4] = Kc * ((f4 + g4) - y[r][4]);
    }

    __syncthreads();   // Gl/Hl staged

    // Woodbury correction: acc -= (y.G[q]) * H[q], q in groups of 3
    #pragma unroll
    for (int qg = 0; qg < NM; qg += 3) {
      float p00 = 0.f, p01 = 0.f, p02 = 0.f, p10 = 0.f, p11 = 0.f, p12 = 0.f;
      #pragma unroll
      for (int c = 0; c < 5; ++c) {
        float gv0 = Gl[(qg + 0) * GPITCH + col + c];
        float gv1 = Gl[(qg + 1) * GPITCH + col + c];
        float gv2 = Gl[(qg + 2) * GPITCH + col + c];
        p00 = fmaf(y[0][c], gv0, p00); p10 = fmaf(y[1][c], gv0, p10);
        p01 = fmaf(y[0][c], gv1, p01); p11 = fmaf(y[1][c], gv1, p11);
        p02 = fmaf(y[0][c], gv2, p02); p12 = fmaf(y[1][c], gv2, p12);
      }
      #pragma unroll
      for (int m = 32; m >= 1; m >>= 1) {
        p00 += __shfl_xor(p00, m, 64);
        p01 += __shfl_xor(p01, m, 64);
        p02 += __shfl_xor(p02, m, 64);
        p10 += __shfl_xor(p10, m, 64);
        p11 += __shfl_xor(p11, m, 64);
        p12 += __shfl_xor(p12, m, 64);
      }
      #pragma unroll
      for (int c = 0; c < 5; ++c) {
        float h0 = Hl[(qg + 0) * GPITCH + col + c];
        float h1 = Hl[(qg + 1) * GPITCH + col + c];
        float h2 = Hl[(qg + 2) * GPITCH + col + c];
        acc[0][c] = fmaf(-p00, h0, acc[0][c]);
        acc[1][c] = fmaf(-p10, h0, acc[1][c]);
        acc[0][c] = fmaf(-p01, h1, acc[0][c]);
        acc[1][c] = fmaf(-p11, h1, acc[1][c]);
        acc[0][c] = fmaf(-p02, h2, acc[0][c]);
        acc[1][c] = fmaf(-p12, h2, acc[1][c]);
      }
    }

    // x = acc; dual updates via z:
    //   eta' = g*(xl'-x') + z ; tau' = al*x' + bA - y - z
    #pragma unroll
    for (int r = 0; r < 2; ++r) {
      #pragma unroll
      for (int c = 0; c < 5; ++c) x[r][c] = acc[r][c];
      float xp = __shfl(x[r][4], prevlane, 64);
      #pragma unroll
      for (int c = 0; c < 5; ++c) {
        float xl = (c == 0) ? xp : x[r][c - 1];
        eta[r][c] = fmaf(g, xl - x[r][c], z[r][c]);
        tau[r][c] = fmaf(al, x[r][c], (bA[r][c] - y[r][c]) - z[r][c]);
      }
    }
  }

  if (live) {
    #pragma unroll
    for (int r = 0; r < 2; ++r) {
      size_t o = (size_t)(row0 + r) * NS + col;
      #pragma unroll
      for (int c = 0; c < 5; ++c) out[o + c] = x[r][c];
    }
  }
}

extern "C" void kernel_launch(void* const* d_in, const int* in_sizes, int n_in,
                              void* d_out, int out_size, void* d_ws, size_t ws_size,
                              hipStream_t stream) {
  const float* b   = (const float*)d_in[0];
  const float* A   = (const float*)d_in[2];
  const float* gam = (const float*)d_in[3];
  const float* lm  = (const float*)d_in[4];
  const float* al  = (const float*)d_in[5];
  float* out = (float*)d_out;
  float* ws  = (float*)d_ws;

  float* cbuf = ws + OFF_C;
  float* Gbuf = ws + OFF_G;
  float* Hbuf = ws + OFF_H;

  k_cinv<<<dim3(NL), dim3(320), 0, stream>>>(al, gam, cbuf);
  k_G   <<<dim3(NL * NM), dim3(320), 0, stream>>>(A, cbuf, Gbuf);
  k_SH  <<<dim3(NL), dim3(128), 0, stream>>>(A, Gbuf, Hbuf);
  k_main<<<dim3(NB / 8), dim3(256), 0, stream>>>(b, A, gam, lm, al,
                                                 Gbuf, Hbuf, out);
}